// Round 1
// baseline (46.434 us; speedup 1.0000x reference)
//
#include <hip/hip_runtime.h>
#include <hip/hip_bf16.h>

#define B_ 256
#define S_ 512
#define H_ 300
#define NL_ 7
#define NT_ 320   // block threads (5 waves); 300 active for H-dim work
#define NCHUNK_ 4
#define SPER_ (S_ / NCHUNK_)   // 128

// ---------------- Kernel A: masked embedding gather + partial sum ----------
// grid (B, NCHUNK), block NT_. partial[(b*NCHUNK + c)*H + t] = sum over this
// chunk's tokens of emb[id][t], id = input_ids*attention_masks.
__global__ __launch_bounds__(NT_) void dan_gather(
    const int* __restrict__ ids, const int* __restrict__ am,
    const float* __restrict__ emb, float* __restrict__ partial) {
  const int b = blockIdx.x, c = blockIdx.y, t = threadIdx.x;
  __shared__ int sid[SPER_];
  const int s0 = c * SPER_;
  for (int s = t; s < SPER_; s += NT_) {
    int off = b * S_ + s0 + s;
    sid[s] = ids[off] * am[off];
  }
  __syncthreads();
  if (t < H_) {
    const float* ep = emb + t;
    float a0 = 0.f, a1 = 0.f, a2 = 0.f, a3 = 0.f;
#pragma unroll 4
    for (int s = 0; s < SPER_; s += 4) {
      int i0 = sid[s], i1 = sid[s + 1], i2 = sid[s + 2], i3 = sid[s + 3];
      a0 += ep[(size_t)i0 * H_];
      a1 += ep[(size_t)i1 * H_];
      a2 += ep[(size_t)i2 * H_];
      a3 += ep[(size_t)i3 * H_];
    }
    partial[(b * NCHUNK_ + c) * H_ + t] = (a0 + a1) + (a2 + a3);
  }
}

// ---------------- Kernel B: reduce partials + 3-layer MLP + logp -----------
// grid B, block NT_. Writes logits to out[1 + b*7 + c], per-row logp to ws.
__global__ __launch_bounds__(NT_) void dan_mlp(
    const float* __restrict__ partial, const int* __restrict__ drop,
    const int* __restrict__ labels,
    const float* __restrict__ W1, const float* __restrict__ b1,
    const float* __restrict__ W2, const float* __restrict__ b2,
    const float* __restrict__ W3, const float* __restrict__ b3,
    float* __restrict__ out, float* __restrict__ perloss) {
  const int b = blockIdx.x, t = threadIdx.x;
  __shared__ float savg[H_];
  __shared__ float sh[H_];
  __shared__ float swred[NT_ / 64];
  __shared__ float snz;
  __shared__ float slog[NL_];

  // nonzeros[b] = sum_s drop_mask[b,s]  (NOTE: dropout only affects divisor)
  int nzp = 0;
  for (int s = t; s < S_; s += NT_) nzp += drop[b * S_ + s];
  for (int o = 32; o > 0; o >>= 1) nzp += __shfl_down(nzp, o, 64);
  if ((t & 63) == 0) swred[t >> 6] = (float)nzp;
  __syncthreads();
  if (t == 0) {
    float s = 0.f;
    for (int w = 0; w < NT_ / 64; ++w) s += swred[w];
    snz = s;
  }
  __syncthreads();

  // avg
  if (t < H_) {
    float s = 0.f;
#pragma unroll
    for (int c = 0; c < NCHUNK_; ++c) s += partial[(b * NCHUNK_ + c) * H_ + t];
    savg[t] = s / snz;
  }
  __syncthreads();

  // h1 = relu(avg @ W1.T + b1):  h1[i] = sum_j W1[i*H+j] * avg[j]
  if (t < H_) {
    float acc = b1[t];
    const float* w = W1 + t * H_;
    for (int j = 0; j < H_; ++j) acc = fmaf(w[j], savg[j], acc);
    sh[t] = fmaxf(acc, 0.f);
  }
  __syncthreads();

  // h2 = relu(h1 @ W2.T + b2)  (write into savg; its h1-phase reads are done)
  if (t < H_) {
    float acc = b2[t];
    const float* w = W2 + t * H_;
    for (int j = 0; j < H_; ++j) acc = fmaf(w[j], sh[j], acc);
    savg[t] = fmaxf(acc, 0.f);
  }
  __syncthreads();

  // logits = h2 @ W3.T + b3
  if (t < NL_) {
    float acc = b3[t];
    const float* w = W3 + t * H_;
    for (int j = 0; j < H_; ++j) acc = fmaf(w[j], savg[j], acc);
    slog[t] = acc;
    out[1 + b * NL_ + t] = acc;
  }
  __syncthreads();

  // log-softmax + per-row logp at label
  if (t == 0) {
    float m = slog[0];
    for (int c = 1; c < NL_; ++c) m = fmaxf(m, slog[c]);
    float se = 0.f;
    for (int c = 0; c < NL_; ++c) se += expf(slog[c] - m);
    int lab = labels[b];
    perloss[b] = slog[lab] - m - logf(se);
  }
}

// ---------------- Kernel C: deterministic loss reduction -------------------
__global__ void dan_loss(const float* __restrict__ perloss,
                         float* __restrict__ out) {
  const int t = threadIdx.x;  // 256 threads
  float v = perloss[t];
  for (int o = 32; o > 0; o >>= 1) v += __shfl_down(v, o, 64);
  __shared__ float r[4];
  if ((t & 63) == 0) r[t >> 6] = v;
  __syncthreads();
  if (t == 0) out[0] = -(r[0] + r[1] + r[2] + r[3]) * (1.0f / B_);
}

extern "C" void kernel_launch(void* const* d_in, const int* in_sizes, int n_in,
                              void* d_out, int out_size, void* d_ws,
                              size_t ws_size, hipStream_t stream) {
  const int* ids = (const int*)d_in[0];
  const int* am = (const int*)d_in[1];
  const int* labels = (const int*)d_in[2];
  const int* drop = (const int*)d_in[3];
  const float* emb = (const float*)d_in[4];
  const float* W1 = (const float*)d_in[5];
  const float* b1 = (const float*)d_in[6];
  const float* W2 = (const float*)d_in[7];
  const float* b2 = (const float*)d_in[8];
  const float* W3 = (const float*)d_in[9];
  const float* b3 = (const float*)d_in[10];
  float* out = (float*)d_out;

  float* partial = (float*)d_ws;                       // [B][NCHUNK][H]
  float* perloss = partial + (size_t)B_ * NCHUNK_ * H_;  // [B]

  dan_gather<<<dim3(B_, NCHUNK_), NT_, 0, stream>>>(ids, am, emb, partial);
  dan_mlp<<<B_, NT_, 0, stream>>>(partial, drop, labels, W1, b1, W2, b2, W3,
                                  b3, out, perloss);
  dan_loss<<<1, B_, 0, stream>>>(perloss, out);
}